// Round 9
// baseline (237.541 us; speedup 1.0000x reference)
//
#include <hip/hip_runtime.h>
#include <stdint.h>

// AM-softmax loss, fused on MI355X (gfx950) — round 9.
//
// vs round 8 (total 212 us = gemm 90 + ~120 us prep_all/finalize; launch
// fusion proved dispatch overhead is NOT the cost — prep_w's 115 MB HBM
// round-trip is):
//  * prep_w / Wb DELETED. gemm loads B fragments directly from fp32 W with
//    inline RNE bf16 conversion (36 coalesced float4 wave-loads, ~144 cvt
//    per wave — amortized over the whole block).
//  * XCD swizzle: cx = bid % 528, ry = bid / 528 (528 % 8 == 0), so all 8
//    ry-replicas of a column group land on the SAME XCD (bid%8 round-robin
//    heuristic) -> W re-reads served by that XCD's L2 (~1.8 MB resident
//    B working set), instead of 8 XCDs each fetching the same bytes.
//  * everything else as round 8: 4-wave blocks, wave owns 48 cols in regs,
//    A double-buffered 2x24 KB via global_load_lds (prefetch ahead of
//    compute), exp2 epilogue (args pre-scaled by S*log2e), per-block
//    coalesced partial store, finalize fuses partial-reduce + fp32 target
//    logit + margin swap + atomicAdd mean.

constexpr int N  = 2048;
constexpr int D  = 192;               // K
constexpr int C  = 100000;
constexpr int KT = D / 32;            // 6 k-tiles of 32
constexpr int TILE = 512;             // elems per 16x32 fragment tile
constexpr int RT16 = C / 16;          // 6250 real 16-col tiles
constexpr int TPG = 12;               // 16-col tiles per block (4 waves x 3)
constexpr int CX = 521;               // col groups: 521*12 = 6252 tiles
constexpr int CXP = 528;              // padded stride for XCD swizzle (mult of 8)
constexpr float PHANTOM = (float)(CX * TPG * 16 - C);   // 32 exact ones
constexpr int BANDS = 4;              // 64-row bands per block
constexpr int RYB = N / (64 * BANDS); // 8 row groups
constexpr int BUF = 4 * KT * TILE;    // 12288 ushort = 24 KB per band buffer

#define S_SCALE 30.0f
#define MARGIN  0.2f
#define S_LOG2E 43.2808512266689f     // 30 * log2(e)

using short8 = __attribute__((ext_vector_type(8))) short;   // 8 bf16 (4 VGPRs)
using f32x4  = __attribute__((ext_vector_type(4))) float;   // MFMA C/D

typedef __attribute__((address_space(1))) const void GV;
typedef __attribute__((address_space(3))) void LV;

__device__ inline unsigned short f2bf(float f) {  // fp32 -> bf16 RNE
  unsigned int u = __float_as_uint(f);
  u += 0x7fffu + ((u >> 16) & 1u);
  return (unsigned short)(u >> 16);
}

// packed fragment index (ushort units) for element (row r, k):
// tile (r>>4, k>>5), lane = (r&15) + ((k>>3)&3)*16, elem k&7.
__device__ inline int pack_idx(int r, int k) {
  return ((r >> 4) * KT + (k >> 5)) * TILE + (((k >> 3) & 3) * 16 + (r & 15)) * 8 + (k & 7);
}

// Sum across each 16-lane DPP row; result valid in all 16 lanes.
__device__ inline float row_sum16(float v) {
  int x;
  x = __float_as_int(v);
  v += __int_as_float(__builtin_amdgcn_update_dpp(0, x, 0x128, 0xF, 0xF, true)); // row_ror:8
  x = __float_as_int(v);
  v += __int_as_float(__builtin_amdgcn_update_dpp(0, x, 0x124, 0xF, 0xF, true)); // row_ror:4
  x = __float_as_int(v);
  v += __int_as_float(__builtin_amdgcn_update_dpp(0, x, 0x04E, 0xF, 0xF, true)); // quad_perm xor2
  x = __float_as_int(v);
  v += __int_as_float(__builtin_amdgcn_update_dpp(0, x, 0x0B1, 0xF, 0xF, true)); // quad_perm xor1
  return v;
}

// ---------------- prep: normalize x rows -> packed bf16 * S*log2e ---------
__global__ __launch_bounds__(256) void prep_x(const float* __restrict__ x,
                                              unsigned short* __restrict__ xnb,
                                              float* __restrict__ out) {
  if (blockIdx.x == 0 && threadIdx.x == 0) out[0] = 0.0f;  // for finalize atomics
  const int row  = blockIdx.x * 4 + (threadIdx.x >> 6);
  const int lane = threadIdx.x & 63;
  const float* xr = x + (size_t)row * D;
  float v0 = xr[lane], v1 = xr[lane + 64], v2 = xr[lane + 128];
  float ss = v0 * v0 + v1 * v1 + v2 * v2;
#pragma unroll
  for (int off = 32; off > 0; off >>= 1) ss += __shfl_xor(ss, off, 64);
  const float inv = rsqrtf(ss) * S_LOG2E;   // fold exp scale into A
  xnb[pack_idx(row, lane)]       = f2bf(v0 * inv);
  xnb[pack_idx(row, lane + 64)]  = f2bf(v1 * inv);
  xnb[pack_idx(row, lane + 128)] = f2bf(v2 * inv);
}

// ---------------- main fused GEMM + exp-rowsum ----------------------------
// 1-D grid CXP*RYB; cx = bid % CXP (dead if >= CX), ry = bid / CXP. All 8
// ry-replicas of a cx share bid%8 -> same XCD (L2 reuse of W). Block = 4
// waves; wave owns 48 cols, B fragments converted fp32->bf16 into registers.
// 4 bands of 64 rows, A double-buffered (24 KB each), DMA prefetch ahead.
__global__ __launch_bounds__(256, 3) void gemm_lse(
    const unsigned short* __restrict__ xnb,  // packed [128 row-tiles][KT][512]
    const float* __restrict__ Wf,            // [C][D] fp32
    float* __restrict__ partial) {           // [CX][N]
  __shared__ alignas(16) unsigned short As[2 * BUF];   // 48 KB (double buffer)
  __shared__ alignas(16) float rs_lds[4][256];         // 4 KB

  const int tid = threadIdx.x;
  const int bid = blockIdx.x;
  const int cx = bid % CXP, ry = bid / CXP;
  if (cx >= CX) return;                      // 7 dead blocks per ry band

  // ---- issue DMA for band 0 into buf 0 (24 KB, contiguous packed) ----
  {
    const unsigned short* slab = xnb + (size_t)(ry * BANDS) * BUF;
#pragma unroll
    for (int i = 0; i < 6; ++i) {            // 1536 x 16 B
      const int chunk = tid + i * 256;
      __builtin_amdgcn_global_load_lds(
          (GV*)((const char*)slab + (size_t)chunk * 16),
          (LV*)((char*)As + (size_t)chunk * 16), 16, 0, 0);
    }
  }

  const int lane = tid & 63, wave = tid >> 6;
  const int m = lane & 15, quad = lane >> 4;

  // ---- B fragments: fp32 W -> bf16 registers (36 coalesced float4 loads) --
  short8 breg[3][KT];
#pragma unroll
  for (int tc = 0; tc < 3; ++tc) {
    const int gt = cx * TPG + wave * 3 + tc;           // wave-uniform tile id
    if (gt < RT16) {
      const float* src = Wf + (size_t)(gt * 16 + m) * D + quad * 8;
#pragma unroll
      for (int ks = 0; ks < KT; ++ks) {
        const float4* s4 = (const float4*)(src + ks * 32);
        float4 f0 = s4[0], f1 = s4[1];
        short8 hv;
        hv[0] = (short)f2bf(f0.x); hv[1] = (short)f2bf(f0.y);
        hv[2] = (short)f2bf(f0.z); hv[3] = (short)f2bf(f0.w);
        hv[4] = (short)f2bf(f1.x); hv[5] = (short)f2bf(f1.y);
        hv[6] = (short)f2bf(f1.z); hv[7] = (short)f2bf(f1.w);
        breg[tc][ks] = hv;
      }
    } else {                                 // phantom tile: exactly zero
      const short8 z = {0, 0, 0, 0, 0, 0, 0, 0};
#pragma unroll
      for (int ks = 0; ks < KT; ++ks) breg[tc][ks] = z;
    }
  }

  const f32x4 zero4 = {0.0f, 0.0f, 0.0f, 0.0f};

  for (int b = 0; b < BANDS; ++b) {
    __syncthreads();   // drains vmcnt: band b's DMA (issued a full band ago)

    // prefetch band b+1 into the other buffer BEFORE compute of band b
    if (b + 1 < BANDS) {
      const unsigned short* slab = xnb + (size_t)(ry * BANDS + b + 1) * BUF;
      char* dst = (char*)&As[((b + 1) & 1) * BUF];
#pragma unroll
      for (int i = 0; i < 6; ++i) {
        const int chunk = tid + i * 256;
        __builtin_amdgcn_global_load_lds(
            (GV*)((const char*)slab + (size_t)chunk * 16),
            (LV*)(dst + (size_t)chunk * 16), 16, 0, 0);
      }
    }

    const unsigned short* Ab = &As[(b & 1) * BUF];

    f32x4 acc[4][3];
#pragma unroll
    for (int a = 0; a < 4; ++a)
#pragma unroll
      for (int c = 0; c < 3; ++c) acc[a][c] = zero4;

#pragma unroll
    for (int ks = 0; ks < KT; ++ks) {
      short8 af[4];
#pragma unroll
      for (int tr = 0; tr < 4; ++tr)
        af[tr] = *(const short8*)(&Ab[(tr * KT + ks) * TILE + lane * 8]);
#pragma unroll
      for (int tr = 0; tr < 4; ++tr)
#pragma unroll
        for (int tc = 0; tc < 3; ++tc)
          acc[tr][tc] = __builtin_amdgcn_mfma_f32_16x16x32_bf16(
              af[tr], breg[tc][ks], acc[tr][tc], 0, 0, 0);
    }

    // ---- epilogue: exp2 (arg pre-scaled; phantom cols give exactly 1) ----
#pragma unroll
    for (int tr = 0; tr < 4; ++tr) {
      float rv0 = 0.f, rv1 = 0.f, rv2 = 0.f, rv3 = 0.f;
#pragma unroll
      for (int tc = 0; tc < 3; ++tc) {
        rv0 += __builtin_amdgcn_exp2f(acc[tr][tc][0]);
        rv1 += __builtin_amdgcn_exp2f(acc[tr][tc][1]);
        rv2 += __builtin_amdgcn_exp2f(acc[tr][tc][2]);
        rv3 += __builtin_amdgcn_exp2f(acc[tr][tc][3]);
      }
      rv0 = row_sum16(rv0);
      rv1 = row_sum16(rv1);
      rv2 = row_sum16(rv2);
      rv3 = row_sum16(rv3);
      if (m == 0) {
        float4 v = make_float4(rv0, rv1, rv2, rv3);
        *(float4*)(&rs_lds[wave][b * 64 + tr * 16 + quad * 4]) = v;
      }
    }
  }

  __syncthreads();  // all waves' rowsums in LDS
  if (tid < 256) {
    const float s = rs_lds[0][tid] + rs_lds[1][tid] + rs_lds[2][tid] + rs_lds[3][tid];
    partial[(size_t)cx * N + ry * 256 + tid] = s;   // coalesced, exclusive
  }
}

// ---------------- finalize: per-row loss + in-kernel mean reduce ----------
// One wave per row (4 rows/block): gather 521 partials + fp32 target logit in
// one shuffle reduction; block-sum -> one atomicAdd into out[0] (pre-zeroed).
__global__ __launch_bounds__(256) void finalize_rows(
    const float* __restrict__ x, const float* __restrict__ W,
    const int* __restrict__ label, const float* __restrict__ partial,
    float* __restrict__ out) {
  const int row  = blockIdx.x * 4 + (threadIdx.x >> 6);
  const int lane = threadIdx.x & 63;
  const float* xr = x + (size_t)row * D;
  float v0 = xr[lane], v1 = xr[lane + 64], v2 = xr[lane + 128];
  float ss = v0 * v0 + v1 * v1 + v2 * v2;
  const int lab = label[row];
  const float* wr = W + (size_t)lab * D;
  float d = v0 * wr[lane] + v1 * wr[lane + 64] + v2 * wr[lane + 128];
  float p = 0.0f;
  for (int s = lane; s < CX; s += 64) p += partial[(size_t)s * N + row];
#pragma unroll
  for (int off = 32; off > 0; off >>= 1) {
    ss += __shfl_xor(ss, off, 64);
    d  += __shfl_xor(d,  off, 64);
    p  += __shfl_xor(p,  off, 64);
  }
  __shared__ float part[4];
  if (lane == 0) {
    const float tgt   = d * rsqrtf(ss);
    const float numer = S_SCALE * (tgt - MARGIN);
    // remove phantom-ones, swap label column's exp for margin-adjusted exp
    const float se = p - PHANTOM - __expf(S_SCALE * tgt) + __expf(numer);
    part[threadIdx.x >> 6] = numer - logf(se);
  }
  __syncthreads();
  if (threadIdx.x == 0) {
    const float blocksum = part[0] + part[1] + part[2] + part[3];
    atomicAdd(out, -blocksum * (1.0f / (float)N));
  }
}

// ---------------- host ----------------------------------------------------
extern "C" void kernel_launch(void* const* d_in, const int* in_sizes, int n_in,
                              void* d_out, int out_size, void* d_ws, size_t ws_size,
                              hipStream_t stream) {
  const float* x     = (const float*)d_in[0];
  const float* W     = (const float*)d_in[1];
  const int*   label = (const int*)d_in[2];
  float*       out   = (float*)d_out;

  char* ws = (char*)d_ws;
  size_t off = 0;
  unsigned short* xnb = (unsigned short*)(ws + off); off += (size_t)N * D * 2;  // 768 KB
  float* partial = (float*)(ws + off); off += (size_t)CX * N * 4;               // 4.3 MB

  prep_x<<<N / 4, 256, 0, stream>>>(x, xnb, out);

  gemm_lse<<<CXP * RYB, 256, 0, stream>>>(xnb, W, partial);

  finalize_rows<<<N / 4, 256, 0, stream>>>(x, W, label, partial, out);
}